// Round 10
// baseline (57.928 us; speedup 1.0000x reference)
//
#include <hip/hip_runtime.h>

#define TOKS 65536
#define ED 64
#define NE 1024
#define CH_STRIDE 4096      // 64*64
#define B_STRIDE 262144     // 64*64*64

typedef __bf16 bf16x8 __attribute__((ext_vector_type(8)));
typedef float f32x16 __attribute__((ext_vector_type(16)));
typedef unsigned short ushort_t;
typedef unsigned int uint_t;

// ws layout:
//   efrag @ 0      : 32ct x 4ks x 64lane x 8 bf16 (hi of -2*emb) [128 KB]
//   enorm @ 131072 : 1024 f32 (np-pairwise ||e||^2, exact)        [4 KB]
//   hist  @ 135168 : 1024 i32                                     [4 KB]
//   loss  @ 139264 : 1 f64                                        [8 B]

__device__ __forceinline__ ushort_t f2bf(float x) {
    uint_t u = __float_as_uint(x);
    uint_t r = u + 0x7FFFu + ((u >> 16) & 1u);   // RNE
    return (ushort_t)(r >> 16);
}

// ---- prep E: wave per code. enorm via shfl-replicated numpy pairwise (exact
// op order: 8 accumulators, 7 sequential stride-8 adds, 3-level tree).
__global__ __launch_bounds__(256) void vq_prep_e(const float* __restrict__ emb,
                                                 ushort_t* __restrict__ efrag,
                                                 float* __restrict__ enorm,
                                                 int* __restrict__ hist,
                                                 double* __restrict__ lossAcc) {
    const int tid = threadIdx.x;
    const int w = tid >> 6, lane = tid & 63;
    const int j = blockIdx.x * 4 + w;

    const float e = emb[j * 64 + lane];
    const float sq = __fmul_rn(e, e);
    float acc = sq;
    acc = __fadd_rn(acc, __shfl_down(sq, 8, 64));
    acc = __fadd_rn(acc, __shfl_down(sq, 16, 64));
    acc = __fadd_rn(acc, __shfl_down(sq, 24, 64));
    acc = __fadd_rn(acc, __shfl_down(sq, 32, 64));
    acc = __fadd_rn(acc, __shfl_down(sq, 40, 64));
    acc = __fadd_rn(acc, __shfl_down(sq, 48, 64));
    acc = __fadd_rn(acc, __shfl_down(sq, 56, 64));
    float x = __fadd_rn(acc, __shfl_down(acc, 1, 64));
    float y = __fadd_rn(x, __shfl_down(x, 2, 64));
    float zn = __fadd_rn(y, __shfl_down(y, 4, 64));
    if (lane == 0) enorm[j] = zn;

    const ushort_t h = f2bf(-2.0f * e);
    const int ct = j >> 5, m = j & 31;
    const int ks = lane >> 4, kh = (lane >> 3) & 1, i = lane & 7;
    efrag[(size_t)((ct * 4 + ks) * 512) + (m + 32 * kh) * 8 + i] = h;

    if (blockIdx.x < 4) hist[blockIdx.x * 256 + tid] = 0;
    if (blockIdx.x == 0 && tid == 0) *lossAcc = 0.0;
}

// ---- fused: two-pass MFMA filter (min, then extract) + exact rescore +
// gather/hist/loss + zq. Block = 32 tokens, 4 waves = 4 code-quarters.
__global__ __launch_bounds__(256, 2) void vq_main(
    const float* __restrict__ z,
    const ushort_t* __restrict__ efrag,
    const float* __restrict__ enorm,
    const float* __restrict__ emb,
    float* __restrict__ zq,
    float* __restrict__ out_idx,
    int* __restrict__ hist,
    double* __restrict__ lossAcc) {
    __shared__ float z_s[64][36];                 // [channel][token]
    __shared__ float smin[4][32];                 // per (quarter, token) d~ min
    __shared__ float s_zn[32];
    __shared__ unsigned long long s_res[32];      // lex-min (d_bits<<10 | j)
    __shared__ uint_t s_cand[192];                // (token<<10) | j
    __shared__ int s_cnt;
    __shared__ double wsum[4];

    const int tid = threadIdx.x;
    const int w = tid >> 6, lane = tid & 63;
    const int t0 = blockIdx.x * 32;
    const int b = t0 >> 12, hw0 = t0 & 4095;
    const float* zbase = z + (size_t)b * B_STRIDE + hw0;

    // stage z tile for rescore/gather (visible after barrier #1)
    {
        const int c = tid >> 2, u0 = (tid & 3) * 8;
        const float* src = zbase + (size_t)c * CH_STRIDE + u0;
        float4 f0 = *(const float4*)(src);
        float4 f1 = *(const float4*)(src + 4);
        *(float4*)&z_s[c][u0] = f0;
        *(float4*)&z_s[c][u0 + 4] = f1;
    }
    if (tid < 32) s_res[tid] = 0xFFFFFFFFFFFFFFFFull;
    if (tid == 0) s_cnt = 0;

    const int n = lane & 31, kh = lane >> 5;

    // B-frag from global (coalesced 128B segments)
    bf16x8 zb[4];
    #pragma unroll
    for (int ks = 0; ks < 4; ++ks) {
        #pragma unroll
        for (int i = 0; i < 8; ++i) {
            union { ushort_t u; __bf16 bh; } ca;
            ca.u = f2bf(zbase[(size_t)(ks * 16 + kh * 8 + i) * CH_STRIDE + n]);
            zb[ks][i] = ca.bh;
        }
    }

    const bf16x8* eg = (const bf16x8*)efrag;

    // ---- pass 1: per-lane running min of d~ (no index tracking at all)
    float vmin = 3.4e38f;
    #pragma unroll
    for (int ct = 0; ct < 8; ++ct) {
        const int gct = w * 8 + ct;
        bf16x8 ah0 = eg[(size_t)(gct * 4 + 0) * 64 + lane];
        bf16x8 ah1 = eg[(size_t)(gct * 4 + 1) * 64 + lane];
        bf16x8 ah2 = eg[(size_t)(gct * 4 + 2) * 64 + lane];
        bf16x8 ah3 = eg[(size_t)(gct * 4 + 3) * 64 + lane];
        f32x16 acc;
        #pragma unroll
        for (int r = 0; r < 16; ++r) acc[r] = 0.25f;
        acc = __builtin_amdgcn_mfma_f32_32x32x16_bf16(ah0, zb[0], acc, 0, 0, 0);
        acc = __builtin_amdgcn_mfma_f32_32x32x16_bf16(ah1, zb[1], acc, 0, 0, 0);
        acc = __builtin_amdgcn_mfma_f32_32x32x16_bf16(ah2, zb[2], acc, 0, 0, 0);
        acc = __builtin_amdgcn_mfma_f32_32x32x16_bf16(ah3, zb[3], acc, 0, 0, 0);
        #pragma unroll
        for (int r = 0; r < 16; ++r) vmin = fminf(vmin, acc[r]);
    }
    vmin = fminf(vmin, __shfl_xor(vmin, 32, 64));  // merge hi halves
    if (kh == 0) smin[w][n] = vmin;
    __syncthreads();

    // per-token threshold over all 4 quarters (raw float, 4e-4 window)
    const float thr = fminf(fminf(smin[0][n], smin[1][n]),
                            fminf(smin[2][n], smin[3][n])) + 4.0e-4f;

    // znorm (8-way sliced, exact np op order) — independent of pass 2
    const int t_loc = tid >> 3, m = tid & 7;
    {
        float a = z_s[m][t_loc];
        float racc = __fmul_rn(a, a);
        #pragma unroll
        for (int i = 1; i < 8; ++i) {
            float av = z_s[m + 8 * i][t_loc];
            racc = __fadd_rn(racc, __fmul_rn(av, av));
        }
        float x1 = __fadd_rn(racc, __shfl_xor(racc, 1, 64));
        float y1 = __fadd_rn(x1, __shfl_xor(x1, 2, 64));
        float zn = __fadd_rn(y1, __shfl_xor(y1, 4, 64));
        if (m == 0) s_zn[t_loc] = zn;
    }

    // ---- pass 2: recompute, extract candidates <= thr (rare)
    #pragma unroll
    for (int ct = 0; ct < 8; ++ct) {
        const int gct = w * 8 + ct;
        bf16x8 ah0 = eg[(size_t)(gct * 4 + 0) * 64 + lane];
        bf16x8 ah1 = eg[(size_t)(gct * 4 + 1) * 64 + lane];
        bf16x8 ah2 = eg[(size_t)(gct * 4 + 2) * 64 + lane];
        bf16x8 ah3 = eg[(size_t)(gct * 4 + 3) * 64 + lane];
        f32x16 acc;
        #pragma unroll
        for (int r = 0; r < 16; ++r) acc[r] = 0.25f;
        acc = __builtin_amdgcn_mfma_f32_32x32x16_bf16(ah0, zb[0], acc, 0, 0, 0);
        acc = __builtin_amdgcn_mfma_f32_32x32x16_bf16(ah1, zb[1], acc, 0, 0, 0);
        acc = __builtin_amdgcn_mfma_f32_32x32x16_bf16(ah2, zb[2], acc, 0, 0, 0);
        acc = __builtin_amdgcn_mfma_f32_32x32x16_bf16(ah3, zb[3], acc, 0, 0, 0);
        float m16 = acc[0];
        #pragma unroll
        for (int r = 1; r < 16; ++r) m16 = fminf(m16, acc[r]);
        if (m16 <= thr) {
            const int jb = gct * 32 + 4 * kh;
            #pragma unroll
            for (int r = 0; r < 16; ++r) {
                if (acc[r] <= thr) {
                    int pos = atomicAdd(&s_cnt, 1);
                    if (pos < 192)
                        s_cand[pos] = ((uint_t)n << 10)
                                      | (uint_t)(jb + (r & 3) + 8 * (r >> 2));
                }
            }
        }
    }
    __syncthreads();

    // ---- compacted exact rescore: one candidate per thread
    {
        const int cnt = s_cnt;
        if (tid < cnt && tid < 192) {
            const uint_t cd = s_cand[tid];
            const int tok = (int)(cd >> 10), j = (int)(cd & 1023u);
            const float* e = emb + (size_t)j * 64;
            float a0 = 0.f;
            #pragma unroll
            for (int k4 = 0; k4 < 64; k4 += 4) {
                float4 e4 = *(const float4*)(e + k4);
                a0 = __fmaf_rn(z_s[k4 + 0][tok], e4.x, a0);
                a0 = __fmaf_rn(z_s[k4 + 1][tok], e4.y, a0);
                a0 = __fmaf_rn(z_s[k4 + 2][tok], e4.z, a0);
                a0 = __fmaf_rn(z_s[k4 + 3][tok], e4.w, a0);
            }
            float d = __fsub_rn(__fadd_rn(s_zn[tok], enorm[j]), 2.0f * a0);
            // d ~ [30,110] > 0: float bits order-monotone; lex (d, j)
            unsigned long long key =
                ((unsigned long long)__float_as_uint(d) << 10)
                | (unsigned long long)j;
            atomicMin(&s_res[tok], key);
        }
    }
    __syncthreads();

    // ---- gather + loss (8 threads/token, interleaved channels) + outputs
    const int bj = (int)(s_res[t_loc] & 1023u);
    if (m == 0) {
        out_idx[t0 + t_loc] = (float)bj;
        atomicAdd(&hist[bj], 1);
    }
    double ls = 0.0;
    {
        const float* e = emb + (size_t)bj * 64;
        #pragma unroll
        for (int i = 0; i < 8; ++i) {
            const int k = m + 8 * i;
            float ev = e[k];
            float zv = z_s[k][t_loc];
            z_s[k][t_loc] = ev;                    // tile becomes z_q
            float df = ev - zv;
            ls += (double)(df * df);
        }
    }
    #pragma unroll
    for (int off = 32; off > 0; off >>= 1) ls += __shfl_down(ls, off, 64);
    if (lane == 0) wsum[w] = ls;
    __syncthreads();                               // z_s fully z_q; wsum ready
    if (tid == 0)
        atomicAdd(lossAcc, wsum[0] + wsum[1] + wsum[2] + wsum[3]);

    // coalesced z_q store
    {
        const int c = tid >> 2, u0 = (tid & 3) * 8;
        float4 f0 = *(const float4*)&z_s[c][u0];
        float4 f1 = *(const float4*)&z_s[c][u0 + 4];
        float* dst = zq + (size_t)b * B_STRIDE + (size_t)c * CH_STRIDE + hw0 + u0;
        *(float4*)(dst) = f0;
        *(float4*)(dst + 4) = f1;
    }
}

__global__ __launch_bounds__(256) void vq_final(const int* __restrict__ hist,
                                                const double* __restrict__ lossAcc,
                                                float* __restrict__ outs) {
    __shared__ double red[256];
    double acc = 0.0;
    for (int j = threadIdx.x; j < NE; j += 256) {
        double em = (double)hist[j] * (1.0 / 65536.0);
        acc += em * log(em + 1e-10);
    }
    red[threadIdx.x] = acc;
    __syncthreads();
    for (int s = 128; s > 0; s >>= 1) {
        if (threadIdx.x < s) red[threadIdx.x] += red[threadIdx.x + s];
        __syncthreads();
    }
    if (threadIdx.x == 0) {
        outs[0] = (float)(1.25 * (*lossAcc) * (1.0 / 4194304.0));
        outs[1] = (float)exp(-red[0]);
    }
}

extern "C" void kernel_launch(void* const* d_in, const int* in_sizes, int n_in,
                              void* d_out, int out_size, void* d_ws, size_t ws_size,
                              hipStream_t stream) {
    const float* z = (const float*)d_in[0];
    const float* emb = (const float*)d_in[1];
    float* out = (float*)d_out;

    char* ws = (char*)d_ws;
    ushort_t* efrag = (ushort_t*)ws;
    float* enorm = (float*)(ws + 131072);
    int* hist = (int*)(ws + 135168);
    double* lossAcc = (double*)(ws + 139264);

    float* zq = out;                        // [0, 4194304)
    float* scalars = out + 4194304;         // loss, perplexity
    float* out_idx = out + 4194306;         // 65536 indices as float

    vq_prep_e<<<256, 256, 0, stream>>>(emb, efrag, enorm, hist, lossAcc);
    vq_main<<<2048, 256, 0, stream>>>(z, efrag, enorm, emb, zq, out_idx, hist, lossAcc);
    vq_final<<<1, 256, 0, stream>>>(hist, lossAcc, scalars);
}

// Round 11
// 47.257 us; speedup vs baseline: 1.2258x; 1.2258x over previous
//
#include <hip/hip_runtime.h>

#define TOKS 65536
#define ED 64
#define NE 1024
#define CH_STRIDE 4096      // 64*64
#define B_STRIDE 262144     // 64*64*64

typedef __bf16 bf16x8 __attribute__((ext_vector_type(8)));
typedef float f32x16 __attribute__((ext_vector_type(16)));
typedef unsigned short ushort_t;
typedef unsigned int uint_t;

// ws layout:
//   efrag @ 0      : 32ct x 4ks x 64lane x 8 bf16 (hi of -2*emb) [128 KB]
//   enorm @ 131072 : 1024 f32 (np-pairwise ||e||^2, exact)        [4 KB]
//   hist  @ 135168 : 1024 i32                                     [4 KB]
//   loss  @ 139264 : 1 f64                                        [8 B]

__device__ __forceinline__ ushort_t f2bf(float x) {
    uint_t u = __float_as_uint(x);
    uint_t r = u + 0x7FFFu + ((u >> 16) & 1u);   // RNE
    return (ushort_t)(r >> 16);
}

// ---- prep E: wave per code. enorm via shfl-replicated numpy pairwise (exact
// op order: 8 accumulators, 7 sequential stride-8 adds, 3-level tree).
__global__ __launch_bounds__(256) void vq_prep_e(const float* __restrict__ emb,
                                                 ushort_t* __restrict__ efrag,
                                                 float* __restrict__ enorm,
                                                 int* __restrict__ hist,
                                                 double* __restrict__ lossAcc) {
    const int tid = threadIdx.x;
    const int w = tid >> 6, lane = tid & 63;
    const int j = blockIdx.x * 4 + w;

    const float e = emb[j * 64 + lane];
    const float sq = __fmul_rn(e, e);
    float acc = sq;
    acc = __fadd_rn(acc, __shfl_down(sq, 8, 64));
    acc = __fadd_rn(acc, __shfl_down(sq, 16, 64));
    acc = __fadd_rn(acc, __shfl_down(sq, 24, 64));
    acc = __fadd_rn(acc, __shfl_down(sq, 32, 64));
    acc = __fadd_rn(acc, __shfl_down(sq, 40, 64));
    acc = __fadd_rn(acc, __shfl_down(sq, 48, 64));
    acc = __fadd_rn(acc, __shfl_down(sq, 56, 64));
    float x = __fadd_rn(acc, __shfl_down(acc, 1, 64));
    float y = __fadd_rn(x, __shfl_down(x, 2, 64));
    float zn = __fadd_rn(y, __shfl_down(y, 4, 64));
    if (lane == 0) enorm[j] = zn;

    const ushort_t h = f2bf(-2.0f * e);
    const int ct = j >> 5, m = j & 31;
    const int ks = lane >> 4, kh = (lane >> 3) & 1, i = lane & 7;
    efrag[(size_t)((ct * 4 + ks) * 512) + (m + 32 * kh) * 8 + i] = h;

    if (blockIdx.x < 4) hist[blockIdx.x * 256 + tid] = 0;
    if (blockIdx.x == 0 && tid == 0) *lossAcc = 0.0;
}

// ---- fused: MFMA filter (2 token-tiles share each efrag load) + compacted
// exact rescore + gather/hist/loss + zq. Block = 64 tokens, 4 waves = 4
// code-quarters, 1024 blocks. Top-2 keys per (lane,tile) 128-code set.
__global__ __launch_bounds__(256, 4) void vq_main(
    const float* __restrict__ z,
    const ushort_t* __restrict__ efrag,
    const float* __restrict__ enorm,
    const float* __restrict__ emb,
    float* __restrict__ zq,
    float* __restrict__ out_idx,
    int* __restrict__ hist,
    double* __restrict__ lossAcc) {
    __shared__ float z_s[64][68];                 // [channel][token 0..63]
    __shared__ uint_t skey[4][2][32][2][2];       // [wave][tile][n][kh][slot]
    __shared__ float s_zn[64];
    __shared__ unsigned long long s_res[64];      // lex-min (d_bits<<10 | j)
    __shared__ uint_t s_cand[256];                // (token<<10) | j
    __shared__ int s_cnt;
    __shared__ double wsum[4];

    const int tid = threadIdx.x;
    const int w = tid >> 6, lane = tid & 63;
    const int t0 = blockIdx.x * 64;
    const int b = t0 >> 12, hw0 = t0 & 4095;
    const float* zbase = z + (size_t)b * B_STRIDE + hw0;

    // stage z tile (64 ch x 64 tok) for rescore/gather
    {
        const int c = tid >> 2, u0 = (tid & 3) * 16;
        const float* src = zbase + (size_t)c * CH_STRIDE + u0;
        float4 f0 = *(const float4*)(src);
        float4 f1 = *(const float4*)(src + 4);
        float4 f2 = *(const float4*)(src + 8);
        float4 f3 = *(const float4*)(src + 12);
        float4* dst = (float4*)&z_s[c][u0];
        dst[0] = f0; dst[1] = f1; dst[2] = f2; dst[3] = f3;
    }
    if (tid < 64) s_res[tid] = 0xFFFFFFFFFFFFFFFFull;
    if (tid == 0) s_cnt = 0;

    const int n = lane & 31, kh = lane >> 5;

    // B-frags from global: tiles A (tok n) and B (tok 32+n)
    bf16x8 zbA[4], zbB[4];
    #pragma unroll
    for (int ks = 0; ks < 4; ++ks) {
        #pragma unroll
        for (int i = 0; i < 8; ++i) {
            const size_t off = (size_t)(ks * 16 + kh * 8 + i) * CH_STRIDE;
            union { ushort_t u; __bf16 bh; } ca, cb;
            ca.u = f2bf(zbase[off + n]);
            cb.u = f2bf(zbase[off + 32 + n]);
            zbA[ks][i] = ca.bh;
            zbB[ks][i] = cb.bh;
        }
    }

    uint_t kA0 = 0xFFFFFFFFu, kA1 = 0xFFFFFFFFu;
    uint_t kB0 = 0xFFFFFFFFu, kB1 = 0xFFFFFFFFu;
    const bf16x8* eg = (const bf16x8*)efrag;

    // prologue: load ct=0 fragments
    bf16x8 ah0 = eg[(size_t)((w * 8) * 4 + 0) * 64 + lane];
    bf16x8 ah1 = eg[(size_t)((w * 8) * 4 + 1) * 64 + lane];
    bf16x8 ah2 = eg[(size_t)((w * 8) * 4 + 2) * 64 + lane];
    bf16x8 ah3 = eg[(size_t)((w * 8) * 4 + 3) * 64 + lane];

    for (int ct = 0; ct < 8; ++ct) {
        const int gct = w * 8 + ct;
        bf16x8 nx0, nx1, nx2, nx3;
        if (ct < 7) {                              // prefetch next ct
            nx0 = eg[(size_t)((gct + 1) * 4 + 0) * 64 + lane];
            nx1 = eg[(size_t)((gct + 1) * 4 + 1) * 64 + lane];
            nx2 = eg[(size_t)((gct + 1) * 4 + 2) * 64 + lane];
            nx3 = eg[(size_t)((gct + 1) * 4 + 3) * 64 + lane];
        }
        const int jb = gct * 32 + 4 * kh;

        f32x16 accA;
        #pragma unroll
        for (int r = 0; r < 16; ++r) accA[r] = 0.25f;
        accA = __builtin_amdgcn_mfma_f32_32x32x16_bf16(ah0, zbA[0], accA, 0, 0, 0);
        accA = __builtin_amdgcn_mfma_f32_32x32x16_bf16(ah1, zbA[1], accA, 0, 0, 0);
        accA = __builtin_amdgcn_mfma_f32_32x32x16_bf16(ah2, zbA[2], accA, 0, 0, 0);
        accA = __builtin_amdgcn_mfma_f32_32x32x16_bf16(ah3, zbA[3], accA, 0, 0, 0);

        f32x16 accB;
        #pragma unroll
        for (int r = 0; r < 16; ++r) accB[r] = 0.25f;
        accB = __builtin_amdgcn_mfma_f32_32x32x16_bf16(ah0, zbB[0], accB, 0, 0, 0);
        accB = __builtin_amdgcn_mfma_f32_32x32x16_bf16(ah1, zbB[1], accB, 0, 0, 0);
        accB = __builtin_amdgcn_mfma_f32_32x32x16_bf16(ah2, zbB[2], accB, 0, 0, 0);
        accB = __builtin_amdgcn_mfma_f32_32x32x16_bf16(ah3, zbB[3], accB, 0, 0, 0);

        // two independent top-2 insertion chains (3 ops/value each)
        #pragma unroll
        for (int r = 0; r < 16; ++r) {
            const uint_t jbits = (uint_t)(jb + (r & 3) + 8 * (r >> 2));
            uint_t keyA = (__float_as_uint(accA[r]) & 0xFFFFFC00u) | jbits;
            uint_t mxA = max(kA0, keyA);
            kA1 = min(kA1, mxA);
            kA0 = min(kA0, keyA);
            uint_t keyB = (__float_as_uint(accB[r]) & 0xFFFFFC00u) | jbits;
            uint_t mxB = max(kB0, keyB);
            kB1 = min(kB1, mxB);
            kB0 = min(kB0, keyB);
        }
        ah0 = nx0; ah1 = nx1; ah2 = nx2; ah3 = nx3;
    }

    skey[w][0][n][kh][0] = kA0; skey[w][0][n][kh][1] = kA1;
    skey[w][1][n][kh][0] = kB0; skey[w][1][n][kh][1] = kB1;
    __syncthreads();

    // ---- threshold + candidate compaction + znorm (4 threads per token)
    const int t_loc = tid >> 2, m = tid & 3;
    const int tile = t_loc >> 5, nn = t_loc & 31;
    {
        uint_t ck[4];
        ck[0] = skey[m][tile][nn][0][0];
        ck[1] = skey[m][tile][nn][0][1];
        ck[2] = skey[m][tile][nn][1][0];
        ck[3] = skey[m][tile][nn][1][1];
        uint_t kmin = min(min(ck[0], ck[1]), min(ck[2], ck[3]));
        kmin = min(kmin, (uint_t)__shfl_xor((int)kmin, 1, 64));
        kmin = min(kmin, (uint_t)__shfl_xor((int)kmin, 2, 64));
        const float thr = __uint_as_float(kmin & 0xFFFFFC00u) + 4.0e-4f;
        #pragma unroll
        for (int s = 0; s < 4; ++s) {
            if (__uint_as_float(ck[s] & 0xFFFFFC00u) <= thr) {
                int pos = atomicAdd(&s_cnt, 1);
                if (pos < 256)
                    s_cand[pos] = ((uint_t)t_loc << 10) | (ck[s] & 1023u);
            }
        }
    }
    {   // znorm: np pairwise, exact op order; thread m owns slices m and m+4
        float a0 = z_s[m][t_loc];
        float ra = __fmul_rn(a0, a0);
        float b0 = z_s[m + 4][t_loc];
        float rb = __fmul_rn(b0, b0);
        #pragma unroll
        for (int i = 1; i < 8; ++i) {
            float av = z_s[m + 8 * i][t_loc];
            ra = __fadd_rn(ra, __fmul_rn(av, av));
            float bv = z_s[m + 4 + 8 * i][t_loc];
            rb = __fadd_rn(rb, __fmul_rn(bv, bv));
        }
        float xa = __fadd_rn(ra, __shfl_xor(ra, 1, 64));
        float A = __fadd_rn(xa, __shfl_xor(xa, 2, 64));
        float xb = __fadd_rn(rb, __shfl_xor(rb, 1, 64));
        float B = __fadd_rn(xb, __shfl_xor(xb, 2, 64));
        if (m == 0) s_zn[t_loc] = __fadd_rn(A, B);
    }
    __syncthreads();

    // ---- compacted exact rescore: one candidate per thread
    {
        const int cnt = s_cnt;
        if (tid < cnt && tid < 256) {
            const uint_t cd = s_cand[tid];
            const int tok = (int)(cd >> 10), j = (int)(cd & 1023u);
            const float* e = emb + (size_t)j * 64;
            float a0 = 0.f;
            #pragma unroll
            for (int k4 = 0; k4 < 64; k4 += 4) {
                float4 e4 = *(const float4*)(e + k4);
                a0 = __fmaf_rn(z_s[k4 + 0][tok], e4.x, a0);
                a0 = __fmaf_rn(z_s[k4 + 1][tok], e4.y, a0);
                a0 = __fmaf_rn(z_s[k4 + 2][tok], e4.z, a0);
                a0 = __fmaf_rn(z_s[k4 + 3][tok], e4.w, a0);
            }
            float d = __fsub_rn(__fadd_rn(s_zn[tok], enorm[j]), 2.0f * a0);
            unsigned long long key =
                ((unsigned long long)__float_as_uint(d) << 10)
                | (unsigned long long)j;
            atomicMin(&s_res[tok], key);
        }
    }
    __syncthreads();

    // ---- gather + loss (4 threads/token, interleaved channels) + outputs
    const int bj = (int)(s_res[t_loc] & 1023u);
    if (m == 0) {
        out_idx[t0 + t_loc] = (float)bj;
        atomicAdd(&hist[bj], 1);
    }
    double ls = 0.0;
    {
        const float* e = emb + (size_t)bj * 64;
        #pragma unroll
        for (int i = 0; i < 16; ++i) {
            const int k = m + 4 * i;
            float ev = e[k];
            float zv = z_s[k][t_loc];
            z_s[k][t_loc] = ev;                    // tile becomes z_q
            float df = ev - zv;
            ls += (double)(df * df);
        }
    }
    #pragma unroll
    for (int off = 32; off > 0; off >>= 1) ls += __shfl_down(ls, off, 64);
    if (lane == 0) wsum[w] = ls;
    __syncthreads();                               // z_s fully z_q; wsum ready
    if (tid == 0)
        atomicAdd(lossAcc, wsum[0] + wsum[1] + wsum[2] + wsum[3]);

    // coalesced z_q store
    {
        const int c = tid >> 2, u0 = (tid & 3) * 16;
        const float4* s4 = (const float4*)&z_s[c][u0];
        float4 f0 = s4[0], f1 = s4[1], f2 = s4[2], f3 = s4[3];
        float* dst = zq + (size_t)b * B_STRIDE + (size_t)c * CH_STRIDE + hw0 + u0;
        *(float4*)(dst) = f0;
        *(float4*)(dst + 4) = f1;
        *(float4*)(dst + 8) = f2;
        *(float4*)(dst + 12) = f3;
    }
}

__global__ __launch_bounds__(256) void vq_final(const int* __restrict__ hist,
                                                const double* __restrict__ lossAcc,
                                                float* __restrict__ outs) {
    __shared__ double red[256];
    double acc = 0.0;
    for (int j = threadIdx.x; j < NE; j += 256) {
        double em = (double)hist[j] * (1.0 / 65536.0);
        acc += em * log(em + 1e-10);
    }
    red[threadIdx.x] = acc;
    __syncthreads();
    for (int s = 128; s > 0; s >>= 1) {
        if (threadIdx.x < s) red[threadIdx.x] += red[threadIdx.x + s];
        __syncthreads();
    }
    if (threadIdx.x == 0) {
        outs[0] = (float)(1.25 * (*lossAcc) * (1.0 / 4194304.0));
        outs[1] = (float)exp(-red[0]);
    }
}

extern "C" void kernel_launch(void* const* d_in, const int* in_sizes, int n_in,
                              void* d_out, int out_size, void* d_ws, size_t ws_size,
                              hipStream_t stream) {
    const float* z = (const float*)d_in[0];
    const float* emb = (const float*)d_in[1];
    float* out = (float*)d_out;

    char* ws = (char*)d_ws;
    ushort_t* efrag = (ushort_t*)ws;
    float* enorm = (float*)(ws + 131072);
    int* hist = (int*)(ws + 135168);
    double* lossAcc = (double*)(ws + 139264);

    float* zq = out;                        // [0, 4194304)
    float* scalars = out + 4194304;         // loss, perplexity
    float* out_idx = out + 4194306;         // 65536 indices as float

    vq_prep_e<<<256, 256, 0, stream>>>(emb, efrag, enorm, hist, lossAcc);
    vq_main<<<1024, 256, 0, stream>>>(z, efrag, enorm, emb, zq, out_idx, hist, lossAcc);
    vq_final<<<1, 256, 0, stream>>>(hist, lossAcc, scalars);
}